// Round 1
// baseline (751.161 us; speedup 1.0000x reference)
//
#include <hip/hip_runtime.h>
#include <hip/hip_bf16.h>
#include <cstdint>
#include <cstddef>

#define E_EXPERTS 24
#define D_DIM 1024
#define F_DIM 2048

#define BM 128
#define BN 128
#define BK 64
#define LDK 72   // BK + 8 pad, keeps 16B alignment (144B row stride)

typedef float f32x4 __attribute__((ext_vector_type(4)));
typedef short s16x8 __attribute__((ext_vector_type(8)));

static __device__ __forceinline__ unsigned short f2bf(float f) {
    union { float f; unsigned u; } v; v.f = f;
    unsigned r = v.u + 0x7FFFu + ((v.u >> 16) & 1u);   // RNE
    return (unsigned short)(r >> 16);
}

// ---------------- gate + top-3 (one wave per token) ----------------
__global__ __launch_bounds__(256) void k_gate(const float* __restrict__ x,
                                              const float* __restrict__ gw,
                                              int* __restrict__ top3, int T) {
    int wave = (blockIdx.x * 256 + threadIdx.x) >> 6;
    int lane = threadIdx.x & 63;
    if (wave >= T) return;
    const float* xr = x + (size_t)wave * D_DIM;
    f32x4 xv[4];
#pragma unroll
    for (int i = 0; i < 4; ++i) xv[i] = *(const f32x4*)(xr + i * 256 + lane * 4);
    float v0 = -1e30f, v1 = -1e30f, v2 = -1e30f;
    int i0 = 0, i1 = 0, i2 = 0;
    for (int e = 0; e < E_EXPERTS; ++e) {
        const float* gr = gw + (size_t)e * D_DIM;
        float d = 0.f;
#pragma unroll
        for (int i = 0; i < 4; ++i) {
            f32x4 g = *(const f32x4*)(gr + i * 256 + lane * 4);
            d += xv[i].x * g.x + xv[i].y * g.y + xv[i].z * g.z + xv[i].w * g.w;
        }
#pragma unroll
        for (int s = 32; s > 0; s >>= 1) d += __shfl_xor(d, s, 64);
        // strict > keeps earlier (lower) expert index on ties, matching lax.top_k
        if (d > v0)      { v2 = v1; i2 = i1; v1 = v0; i1 = i0; v0 = d; i0 = e; }
        else if (d > v1) { v2 = v1; i2 = i1; v1 = d;  i1 = e; }
        else if (d > v2) { v2 = d;  i2 = e; }
    }
    if (lane == 0) {
        top3[wave * 3 + 0] = i0;
        top3[wave * 3 + 1] = i1;
        top3[wave * 3 + 2] = i2;
    }
}

// ---------------- count + exclusive prefix (single block) ----------------
__global__ __launch_bounds__(256) void k_count(const int* __restrict__ top3,
                                               int* __restrict__ offs,
                                               int* __restrict__ cnt, int T) {
    __shared__ int lc[E_EXPERTS];
    int t = threadIdx.x;
    if (t < E_EXPERTS) lc[t] = 0;
    __syncthreads();
    for (int i = t; i < T * 3; i += 256) atomicAdd(&lc[top3[i]], 1);
    __syncthreads();
    if (t == 0) {
        int acc = 0;
        for (int e = 0; e < E_EXPERTS; ++e) { offs[e] = acc; acc += lc[e]; }
        offs[E_EXPERTS] = acc;
    }
    if (t < E_EXPERTS) cnt[t] = 0;   // reset for k_fill's reservations
}

// ---------------- fill routing lists (block-local reservation) ----------------
__global__ __launch_bounds__(256) void k_fill(const int* __restrict__ top3,
                                              const int* __restrict__ offs,
                                              int* __restrict__ cnt,
                                              int* __restrict__ list,
                                              int* __restrict__ tslot, int T) {
    __shared__ int lc[E_EXPERTS], lbase[E_EXPERTS];
    int t = threadIdx.x;
    if (t < E_EXPERTS) lc[t] = 0;
    __syncthreads();
    int tok = blockIdx.x * 256 + t;
    int e[3], li[3];
    if (tok < T) {
#pragma unroll
        for (int k = 0; k < 3; ++k) {
            e[k] = top3[tok * 3 + k];
            li[k] = atomicAdd(&lc[e[k]], 1);
        }
    }
    __syncthreads();
    if (t < E_EXPERTS) lbase[t] = atomicAdd(&cnt[t], lc[t]);
    __syncthreads();
    if (tok < T) {
#pragma unroll
        for (int k = 0; k < 3; ++k) {
            int slot = offs[e[k]] + lbase[e[k]] + li[k];
            list[slot] = tok;
            tslot[tok * 3 + k] = slot;
        }
    }
}

// ---------------- grouped GEMM1: H = relu(X_e @ W1[e] + b1[e]) ----------------
__global__ __launch_bounds__(256) void k_gemm1(const float* __restrict__ x,
                                               const float* __restrict__ w1,
                                               const float* __restrict__ b1,
                                               const int* __restrict__ offs,
                                               const int* __restrict__ list,
                                               unsigned short* __restrict__ H) {
    const int e = blockIdx.z, mtile = blockIdx.y, ntile = blockIdx.x;
    const int offE = offs[e], cntE = offs[e + 1] - offE;
    if (mtile * BM >= cntE) return;
    __shared__ unsigned short Asl[BM][LDK];
    __shared__ unsigned short Bsl[BN][LDK];
    const int tid = threadIdx.x, lane = tid & 63, wid = tid >> 6;
    const int wm = wid >> 1, wn = wid & 1;
    const float* W = w1 + (size_t)e * D_DIM * F_DIM;

    const int ar = tid >> 1, ahalf = tid & 1;
    int arow = mtile * BM + ar;
    int tokA = (arow < cntE) ? list[offE + arow] : list[offE];
    const float* xr = x + (size_t)tokA * D_DIM;

    const int bn = tid & 127, bk = tid >> 7;
    const int ncol = ntile * BN + bn;

    f32x4 acc[4][4];
#pragma unroll
    for (int i = 0; i < 4; ++i)
#pragma unroll
        for (int j = 0; j < 4; ++j) acc[i][j] = (f32x4){0.f, 0.f, 0.f, 0.f};

    for (int kt = 0; kt < D_DIM / BK; ++kt) {
        const int kb = kt * BK;
        // stage A (gathered token rows, fp32 -> bf16)
#pragma unroll
        for (int j = 0; j < 4; ++j) {
            f32x4 a0 = *(const f32x4*)(xr + kb + ahalf * 32 + j * 8);
            f32x4 a1 = *(const f32x4*)(xr + kb + ahalf * 32 + j * 8 + 4);
            s16x8 p;
            p[0] = (short)f2bf(a0.x); p[1] = (short)f2bf(a0.y);
            p[2] = (short)f2bf(a0.z); p[3] = (short)f2bf(a0.w);
            p[4] = (short)f2bf(a1.x); p[5] = (short)f2bf(a1.y);
            p[6] = (short)f2bf(a1.z); p[7] = (short)f2bf(a1.w);
            *(s16x8*)&Asl[ar][ahalf * 32 + j * 8] = p;
        }
        // stage B^T: Bsl[n][k] from W[k][n] (coalesced over n)
#pragma unroll
        for (int j8 = 0; j8 < 4; ++j8) {
            s16x8 p;
#pragma unroll
            for (int j = 0; j < 8; ++j) {
                float f = W[(size_t)(kb + bk * 32 + j8 * 8 + j) * F_DIM + ncol];
                p[j] = (short)f2bf(f);
            }
            *(s16x8*)&Bsl[bn][bk * 32 + j8 * 8] = p;
        }
        __syncthreads();
#pragma unroll
        for (int kk = 0; kk < 2; ++kk) {
            s16x8 fa[4], fb[4];
            const int k0 = kk * 32 + (lane >> 4) * 8;
#pragma unroll
            for (int mi = 0; mi < 4; ++mi)
                fa[mi] = *(const s16x8*)&Asl[wm * 64 + mi * 16 + (lane & 15)][k0];
#pragma unroll
            for (int ni = 0; ni < 4; ++ni)
                fb[ni] = *(const s16x8*)&Bsl[wn * 64 + ni * 16 + (lane & 15)][k0];
#pragma unroll
            for (int mi = 0; mi < 4; ++mi)
#pragma unroll
                for (int ni = 0; ni < 4; ++ni)
                    acc[mi][ni] = __builtin_amdgcn_mfma_f32_16x16x32_bf16(
                        fa[mi], fb[ni], acc[mi][ni], 0, 0, 0);
        }
        __syncthreads();
    }
    const float* bias = b1 + (size_t)e * F_DIM;
#pragma unroll
    for (int ni = 0; ni < 4; ++ni) {
        int c = ntile * BN + wn * 64 + ni * 16 + (lane & 15);
        float bv = bias[c];
#pragma unroll
        for (int mi = 0; mi < 4; ++mi) {
            int rl = wm * 64 + mi * 16 + ((lane >> 4) << 2);
#pragma unroll
            for (int i = 0; i < 4; ++i) {
                int rowe = mtile * BM + rl + i;
                if (rowe < cntE) {
                    float h = acc[mi][ni][i] + bv;
                    h = h > 0.f ? h : 0.f;
                    H[(size_t)(offE + rowe) * F_DIM + c] = f2bf(h);
                }
            }
        }
    }
}

// ---------------- grouped GEMM2: Y = H_e @ W2[e] + b2[e] ----------------
__global__ __launch_bounds__(256) void k_gemm2(const unsigned short* __restrict__ H,
                                               const float* __restrict__ w2,
                                               const float* __restrict__ b2,
                                               const int* __restrict__ offs,
                                               float* __restrict__ Y) {
    const int e = blockIdx.z, mtile = blockIdx.y, ntile = blockIdx.x;
    const int offE = offs[e], cntE = offs[e + 1] - offE;
    if (mtile * BM >= cntE) return;
    __shared__ unsigned short Asl[BM][LDK];
    __shared__ unsigned short Bsl[BN][LDK];
    const int tid = threadIdx.x, lane = tid & 63, wid = tid >> 6;
    const int wm = wid >> 1, wn = wid & 1;
    const float* W = w2 + (size_t)e * F_DIM * D_DIM;

    const int ar = tid >> 1, ahalf = tid & 1;
    const unsigned short* hr = H + (size_t)(offE + mtile * BM + ar) * F_DIM; // H padded by BM rows
    const int bn = tid & 127, bk = tid >> 7;
    const int ncol = ntile * BN + bn;

    f32x4 acc[4][4];
#pragma unroll
    for (int i = 0; i < 4; ++i)
#pragma unroll
        for (int j = 0; j < 4; ++j) acc[i][j] = (f32x4){0.f, 0.f, 0.f, 0.f};

    for (int kt = 0; kt < F_DIM / BK; ++kt) {
        const int kb = kt * BK;
#pragma unroll
        for (int j = 0; j < 4; ++j)
            *(s16x8*)&Asl[ar][ahalf * 32 + j * 8] =
                *(const s16x8*)(hr + kb + ahalf * 32 + j * 8);
#pragma unroll
        for (int j8 = 0; j8 < 4; ++j8) {
            s16x8 p;
#pragma unroll
            for (int j = 0; j < 8; ++j) {
                float f = W[(size_t)(kb + bk * 32 + j8 * 8 + j) * D_DIM + ncol];
                p[j] = (short)f2bf(f);
            }
            *(s16x8*)&Bsl[bn][bk * 32 + j8 * 8] = p;
        }
        __syncthreads();
#pragma unroll
        for (int kk = 0; kk < 2; ++kk) {
            s16x8 fa[4], fb[4];
            const int k0 = kk * 32 + (lane >> 4) * 8;
#pragma unroll
            for (int mi = 0; mi < 4; ++mi)
                fa[mi] = *(const s16x8*)&Asl[wm * 64 + mi * 16 + (lane & 15)][k0];
#pragma unroll
            for (int ni = 0; ni < 4; ++ni)
                fb[ni] = *(const s16x8*)&Bsl[wn * 64 + ni * 16 + (lane & 15)][k0];
#pragma unroll
            for (int mi = 0; mi < 4; ++mi)
#pragma unroll
                for (int ni = 0; ni < 4; ++ni)
                    acc[mi][ni] = __builtin_amdgcn_mfma_f32_16x16x32_bf16(
                        fa[mi], fb[ni], acc[mi][ni], 0, 0, 0);
        }
        __syncthreads();
    }
    const float* bias = b2 + (size_t)e * D_DIM;
#pragma unroll
    for (int ni = 0; ni < 4; ++ni) {
        int c = ntile * BN + wn * 64 + ni * 16 + (lane & 15);
        float bv = bias[c];
#pragma unroll
        for (int mi = 0; mi < 4; ++mi) {
            int rl = wm * 64 + mi * 16 + ((lane >> 4) << 2);
#pragma unroll
            for (int i = 0; i < 4; ++i) {
                int rowe = mtile * BM + rl + i;
                if (rowe < cntE)
                    Y[(size_t)(offE + rowe) * D_DIM + c] = acc[mi][ni][i] + bv;
            }
        }
    }
}

// ---------------- gather: out[t] = sum_k eg[k] * Y[slot(t,k)] ----------------
__global__ __launch_bounds__(256) void k_gather(const float* __restrict__ Y,
                                                const int* __restrict__ tslot,
                                                float* __restrict__ out, int T) {
    int idx = blockIdx.x * 256 + threadIdx.x;
    int t = idx >> 8, d4 = (idx & 255) * 4;
    if (t >= T) return;
    f32x4 y0 = *(const f32x4*)(Y + (size_t)tslot[t * 3 + 0] * D_DIM + d4);
    f32x4 y1 = *(const f32x4*)(Y + (size_t)tslot[t * 3 + 1] * D_DIM + d4);
    f32x4 y2 = *(const f32x4*)(Y + (size_t)tslot[t * 3 + 2] * D_DIM + d4);
    f32x4 o = y0 * 0.5f + y1 * (1.f / 3.f) + y2 * (1.f / 6.f);
    *(f32x4*)(out + (size_t)t * D_DIM + d4) = o;
}

extern "C" void kernel_launch(void* const* d_in, const int* in_sizes, int n_in,
                              void* d_out, int out_size, void* d_ws, size_t ws_size,
                              hipStream_t stream) {
    const float* x  = (const float*)d_in[0];
    const float* gw = (const float*)d_in[1];
    const float* w1 = (const float*)d_in[2];
    const float* b1 = (const float*)d_in[3];
    const float* w2 = (const float*)d_in[4];
    const float* b2 = (const float*)d_in[5];
    float* out = (float*)d_out;
    const int T = in_sizes[0] / D_DIM;   // 4096

    char* ws = (char*)d_ws;
    int* offs  = (int*)ws;                       // 32 ints (+1 total slot)
    int* cnt   = (int*)(ws + 128);               // 32 ints
    int* top3  = (int*)(ws + 256);               // T*3
    int* tslot = (int*)(ws + 256 + (size_t)T * 3 * 4);
    int* list  = (int*)(ws + 256 + (size_t)T * 3 * 8);
    size_t hoff = (256 + (size_t)T * 3 * 12 + 4095) & ~(size_t)4095;
    unsigned short* H = (unsigned short*)(ws + hoff);
    size_t hbytes = ((size_t)T * 3 + BM) * F_DIM * 2;  // +BM row pad for tile overreads
    size_t yoff = (hoff + hbytes + 4095) & ~(size_t)4095;
    float* Y = (float*)(ws + yoff);

    const int mt = (T + BM - 1) / BM;  // 32 max M-tiles per expert

    k_gate<<<dim3((T * 64 + 255) / 256), 256, 0, stream>>>(x, gw, top3, T);
    k_count<<<1, 256, 0, stream>>>(top3, offs, cnt, T);
    k_fill<<<dim3((T + 255) / 256), 256, 0, stream>>>(top3, offs, cnt, list, tslot, T);
    k_gemm1<<<dim3(F_DIM / BN, mt, E_EXPERTS), 256, 0, stream>>>(x, w1, b1, offs, list, H);
    k_gemm2<<<dim3(D_DIM / BN, mt, E_EXPERTS), 256, 0, stream>>>(H, w2, b2, offs, Y);
    k_gather<<<dim3(T, 1, 1), 256, 0, stream>>>(Y, tslot, out, T);
}